// Round 4
// baseline (322.613 us; speedup 1.0000x reference)
//
#include <hip/hip_runtime.h>

typedef unsigned short u16;
typedef unsigned int u32;
typedef u16 u16x8 __attribute__((ext_vector_type(8)));
typedef u16 u16x4 __attribute__((ext_vector_type(4)));
typedef float f32x4 __attribute__((ext_vector_type(4)));
typedef __bf16 bf16x8 __attribute__((ext_vector_type(8)));

#define NHEAD 12
#define NT 261
#define NGL 197
#define CDIM 768
#define KT 14
#define PS_STRIDE 232
#define VT_STRIDE 232

__device__ __forceinline__ float bf2f(u16 u) {
    u32 x = ((u32)u) << 16;
    float f;
    __builtin_memcpy(&f, &x, 4);
    return f;
}
__device__ __forceinline__ u16 f2bf(float f) {
    u32 x;
    __builtin_memcpy(&x, &f, 4);
    x = (x + 0x7fffu + ((x >> 16) & 1u)) >> 16;
    return (u16)x;
}

#define GLD_LDS16(g, l) \
    __builtin_amdgcn_global_load_lds((const __attribute__((address_space(1))) void*)(g), \
                                     (__attribute__((address_space(3))) void*)(l), 16, 0, 0)
#define WAITV(n) asm volatile("s_waitcnt vmcnt(" #n ")" ::: "memory")
#define BARM() asm volatile("s_barrier" ::: "memory")

// ---------------- fp32 -> bf16 weight conversion ----------------
__global__ __launch_bounds__(256) void convk(const float* __restrict__ in, u16* __restrict__ out, int n4) {
    int i = blockIdx.x * 256 + threadIdx.x;
    if (i >= n4) return;
    float4 v = ((const float4*)in)[i];
    u16x4 o;
    o[0] = f2bf(v.x); o[1] = f2bf(v.y); o[2] = f2bf(v.z); o[3] = f2bf(v.w);
    ((u16x4*)out)[i] = o;
}

// ---------------- LayerNorm (row of 768) -> bf16 ----------------
__global__ __launch_bounds__(256) void ln_k(const float* __restrict__ in, const float* __restrict__ w,
                                            const float* __restrict__ bia, u16* __restrict__ out) {
    int row = blockIdx.x;
    int tid = threadIdx.x;
    const float* r = in + (size_t)row * CDIM;
    float v0 = r[tid], v1 = r[tid + 256], v2 = r[tid + 512];
    float s = v0 + v1 + v2;
    float ss = v0 * v0 + v1 * v1 + v2 * v2;
#pragma unroll
    for (int off = 32; off; off >>= 1) {
        s += __shfl_xor(s, off);
        ss += __shfl_xor(ss, off);
    }
    __shared__ float ls[4], lss[4];
    int wv = tid >> 6;
    if ((tid & 63) == 0) { ls[wv] = s; lss[wv] = ss; }
    __syncthreads();
    s = ls[0] + ls[1] + ls[2] + ls[3];
    ss = lss[0] + lss[1] + lss[2] + lss[3];
    float mu = s * (1.f / 768.f);
    float var = ss * (1.f / 768.f) - mu * mu;
    float inv = rsqrtf(var + 1e-5f);
    u16* o = out + (size_t)row * CDIM;
    o[tid]       = f2bf((v0 - mu) * inv * w[tid]       + bia[tid]);
    o[tid + 256] = f2bf((v1 - mu) * inv * w[tid + 256] + bia[tid + 256]);
    o[tid + 512] = f2bf((v2 - mu) * inv * w[tid + 512] + bia[tid + 512]);
}

// ---------------- 4-deep pipelined MFMA GEMM: C[m,n] = sum_k A[m,k]*B[n,k] ----------------
// BM=BN=128, BK=32, 4 waves (2x2, 64x64 each). 4 LDS buffers, 3-tile prefetch,
// one barrier per K-tile, counted vmcnt (FIFO retire => vmcnt(8) == "tile t landed").
// 16B-slot XOR swizzle (slot ^= (row>>1)&3) applied on the global SOURCE (linear LDS dest
// for global_load_lds) and re-applied on fragment reads (rule #21) -> 2-way banks (free).
// EPI: 0 = plain -> bf16; 1 = +bias +residual(fp32) -> fp32; 2 = +bias +gelu(tanh) -> bf16
template <int EPI>
__global__ __launch_bounds__(256, 2) void gemm3(const u16* __restrict__ A, const u16* __restrict__ Bw,
                                                int M, int N, int K, int nbn,
                                                const float* __restrict__ bias,
                                                const float* __restrict__ resid, void* __restrict__ outp) {
    __shared__ __align__(16) u16 sm[4][8192];   // [buf][A:0..4095 | B:4096..8191] = 64 KiB
    const int tid = threadIdx.x;
    const int nwg = gridDim.x;
    const int q = nwg >> 3, r = nwg & 7;
    const int xcd = blockIdx.x & 7, within = blockIdx.x >> 3;
    const int id2 = (xcd < r ? xcd * (q + 1) : r * (q + 1) + (xcd - r) * q) + within;
    const int bm = id2 / nbn, bn = id2 % nbn;
    const int lane = tid & 63, wv = tid >> 6;
    const int wr = wv >> 1, wc = wv & 1;
    const int l15 = lane & 15, lg = lane >> 4;
    const int arow0 = bm * 128, brow0 = bn * 128;
    const int nt = K >> 5;                      // K-tiles of 32 (>= 4 for all our GEMMs)

    // staging coords: thread covers LDS bytes {tid*16, 4096+tid*16} per operand
    const int srow = tid >> 2;                  // row for issue 0; +64 for issue 1
    const int sslot = tid & 3;
    const int sk0 = (sslot ^ ((srow >> 1) & 3)) * 8;   // pre-swizzled source k-offset (u16)
    int arA0 = arow0 + srow;        if (arA0 >= M) arA0 = M - 1;
    int arA1 = arow0 + srow + 64;   if (arA1 >= M) arA1 = M - 1;
    const u16* gA0 = A + (size_t)arA0 * K + sk0;
    const u16* gA1 = A + (size_t)arA1 * K + sk0;
    const u16* gB0 = Bw + (size_t)(brow0 + srow) * K + sk0;
    const u16* gB1 = Bw + (size_t)(brow0 + srow + 64) * K + sk0;
    const int lo0 = tid * 8, lo1 = 2048 + tid * 8;

    auto STAGE = [&](int tt) {
        u16* b = sm[tt & 3];
        const size_t ko = (size_t)tt * 32;
        GLD_LDS16(gA0 + ko, b + lo0);
        GLD_LDS16(gA1 + ko, b + lo1);
        GLD_LDS16(gB0 + ko, b + 4096 + lo0);
        GLD_LDS16(gB1 + ko, b + 4096 + lo1);
    };

    f32x4 acc[4][4] = {};
    const int xorv = (lg ^ ((l15 >> 1) & 3)) << 3;     // u16 units, row-independent per lane

    STAGE(0); STAGE(1); STAGE(2);
    for (int t = 0; t < nt; ++t) {
        // FIFO vmcnt: exactly (#loads issued after stage(t)) may remain in flight
        if (t + 2 < nt) { WAITV(8); } else if (t + 1 < nt) { WAITV(4); } else { WAITV(0); }
        BARM();                                 // stage(t) visible to all; buf[(t-1)&3] released
        if (t + 3 < nt) STAGE(t + 3);
        const u16* bufp = sm[t & 3];
        bf16x8 af[4], bfr[4];
#pragma unroll
        for (int mi = 0; mi < 4; ++mi)
            af[mi] = *(const bf16x8*)(bufp + (wr * 64 + mi * 16 + l15) * 32 + xorv);
#pragma unroll
        for (int ni = 0; ni < 4; ++ni)
            bfr[ni] = *(const bf16x8*)(bufp + 4096 + (wc * 64 + ni * 16 + l15) * 32 + xorv);
#pragma unroll
        for (int mi = 0; mi < 4; ++mi)
#pragma unroll
            for (int ni = 0; ni < 4; ++ni)
                acc[mi][ni] = __builtin_amdgcn_mfma_f32_16x16x32_bf16(af[mi], bfr[ni], acc[mi][ni], 0, 0, 0);
    }

#pragma unroll
    for (int mi = 0; mi < 4; ++mi) {
        int row0 = arow0 + wr * 64 + mi * 16 + lg * 4;
#pragma unroll
        for (int ni = 0; ni < 4; ++ni) {
            int col = brow0 + wc * 64 + ni * 16 + l15;
            float bb = (EPI == 0) ? 0.f : bias[col];
#pragma unroll
            for (int rr = 0; rr < 4; ++rr) {
                int row = row0 + rr;
                if (row < M) {
                    float v = acc[mi][ni][rr] + bb;
                    if (EPI == 2) {
                        float z = v + 0.044715f * v * v * v;
                        v = v / (1.f + __expf(-1.5957691216f * z));   // tanh-gelu (dev ~3e-3)
                    }
                    if (EPI == 1) {
                        v += resid[(size_t)row * N + col];
                        ((float*)outp)[(size_t)row * N + col] = v;
                    } else {
                        ((u16*)outp)[(size_t)row * N + col] = f2bf(v);
                    }
                }
            }
        }
    }
}

// ---------------- Global attention via MFMA ----------------
__global__ __launch_bounds__(256) void attn_global_mfma(const u16* __restrict__ qkv, u16* __restrict__ Z) {
    __shared__ __align__(16) u16 lds0[4 * 16 * PS_STRIDE];
    __shared__ __align__(16) u16 Vt[64 * VT_STRIDE];
    const int tid = threadIdx.x;
    const int blk = blockIdx.x;
    const int qt = blk & 3;
    const int bh = blk >> 2;
    const int h = bh % NHEAD, b = bh / NHEAD;
    const int lane = tid & 63, wv = tid >> 6;
    const int l15 = lane & 15, lg = lane >> 4;
    const u16* base = qkv + (size_t)b * NT * 2304;

    for (int c = tid; c < 224 * 8; c += 256) {
        int row = c >> 3, ch = c & 7;
        u16x8 v = {};
        if (row < NGL) v = *(const u16x8*)(base + (size_t)row * 2304 + 768 + h * 64 + ch * 8);
        int byte = row * 128 + ((ch * 16) ^ ((row & 7) << 4));
        *(u16x8*)((char*)lds0 + byte) = v;
    }
    for (int c = tid; c < 112 * 8; c += 256) {
        int mp = c >> 3, dch = c & 7;
        int m0 = mp * 2;
        u16x8 a0 = {}, a1 = {};
        if (m0 < NGL)     a0 = *(const u16x8*)(base + (size_t)m0 * 2304 + 1536 + h * 64 + dch * 8);
        if (m0 + 1 < NGL) a1 = *(const u16x8*)(base + (size_t)(m0 + 1) * 2304 + 1536 + h * 64 + dch * 8);
#pragma unroll
        for (int j = 0; j < 8; ++j) {
            u32 pk = (u32)a0[j] | ((u32)a1[j] << 16);
            *(u32*)((char*)Vt + (size_t)(dch * 8 + j) * (VT_STRIDE * 2) + m0 * 2) = pk;
        }
    }
    const int q0 = qt * 64 + wv * 16;
    int qrow = q0 + l15; if (qrow > NGL - 1) qrow = NGL - 1;
    bf16x8 aq0 = *(const bf16x8*)(base + (size_t)qrow * 2304 + h * 64 + lg * 8);
    bf16x8 aq1 = *(const bf16x8*)(base + (size_t)qrow * 2304 + h * 64 + 32 + lg * 8);
    __syncthreads();

    f32x4 s[KT];
    const int sw = (l15 & 7) << 4;
#pragma unroll
    for (int t = 0; t < KT; ++t) {
        const char* krow = (const char*)lds0 + (t * 16 + l15) * 128;
        bf16x8 bk0 = *(const bf16x8*)(krow + ((lg * 16) ^ sw));
        bf16x8 bk1 = *(const bf16x8*)(krow + ((64 + lg * 16) ^ sw));
        f32x4 acc = {};
        acc = __builtin_amdgcn_mfma_f32_16x16x32_bf16(aq0, bk0, acc, 0, 0, 0);
        acc = __builtin_amdgcn_mfma_f32_16x16x32_bf16(aq1, bk1, acc, 0, 0, 0);
        s[t] = acc * 0.125f;
    }
    float mx[4] = {-1e30f, -1e30f, -1e30f, -1e30f};
#pragma unroll
    for (int t = 0; t < KT; ++t)
#pragma unroll
        for (int r = 0; r < 4; ++r) mx[r] = fmaxf(mx[r], s[t][r]);
#pragma unroll
    for (int off = 1; off < 16; off <<= 1)
#pragma unroll
        for (int r = 0; r < 4; ++r) mx[r] = fmaxf(mx[r], __shfl_xor(mx[r], off));
    float sum[4] = {};
#pragma unroll
    for (int t = 0; t < KT; ++t) {
        bool valid = (t * 16 + l15) < NGL;
#pragma unroll
        for (int r = 0; r < 4; ++r) {
            float e = valid ? __expf(s[t][r] - mx[r]) : 0.f;
            s[t][r] = e;
            sum[r] += e;
        }
    }
#pragma unroll
    for (int off = 1; off < 16; off <<= 1)
#pragma unroll
        for (int r = 0; r < 4; ++r) sum[r] += __shfl_xor(sum[r], off);
    float inv[4];
#pragma unroll
    for (int r = 0; r < 4; ++r) inv[r] = 1.f / sum[r];

    __syncthreads();
    u16* Pw = lds0 + wv * 16 * PS_STRIDE;
#pragma unroll
    for (int t = 0; t < KT; ++t)
#pragma unroll
        for (int r = 0; r < 4; ++r)
            Pw[(4 * lg + r) * PS_STRIDE + t * 16 + l15] = f2bf(s[t][r] * inv[r]);

    f32x4 o[4] = {};
#pragma unroll
    for (int ks = 0; ks < 7; ++ks) {
        bf16x8 pa = *(const bf16x8*)(Pw + l15 * PS_STRIDE + ks * 32 + lg * 8);
#pragma unroll
        for (int dt = 0; dt < 4; ++dt) {
            bf16x8 bv = *(const bf16x8*)((const char*)Vt + (size_t)(dt * 16 + l15) * (VT_STRIDE * 2) + ks * 64 + lg * 16);
            o[dt] = __builtin_amdgcn_mfma_f32_16x16x32_bf16(pa, bv, o[dt], 0, 0, 0);
        }
    }
#pragma unroll
    for (int dt = 0; dt < 4; ++dt)
#pragma unroll
        for (int r = 0; r < 4; ++r) {
            int q = q0 + 4 * lg + r;
            if (q < NGL) Z[((size_t)b * NT + q) * CDIM + h * 64 + dt * 16 + l15] = f2bf(o[dt][r]);
        }
}

// ---------------- Neighborhood attention ----------------
__global__ __launch_bounds__(64) void attn_neigh(const u16* __restrict__ qkv, const float* __restrict__ ps,
                                                 u16* __restrict__ Z) {
    int blk = blockIdx.x;
    int b = blk >> 6, m = blk & 63;
    int lane = threadIdx.x;
    float px = ps[((size_t)b * 64 + m) * 2 + 0] * (1.f / 16.f);
    float py = ps[((size_t)b * 64 + m) * 2 + 1] * (1.f / 16.f);
    int c0 = min(max((int)floorf(px), 0), 13);
    int c1 = min(max((int)ceilf(px), 0), 13);
    int r0 = min(max((int)floorf(py), 0), 13);
    int r1 = min(max((int)ceilf(py), 0), 13);
    int tok[4];
    tok[0] = 1 + r0 * 14 + c0;
    tok[1] = 1 + r1 * 14 + c0;
    tok[2] = 1 + r0 * 14 + c1;
    tok[3] = 1 + r1 * 14 + c1;
    const size_t rowq = ((size_t)b * NT + NGL + m) * 2304;
#pragma unroll 1
    for (int h = 0; h < NHEAD; ++h) {
        float qv = bf2f(qkv[rowq + h * 64 + lane]);
        float a[4];
#pragma unroll
        for (int j = 0; j < 4; ++j) {
            float p = qv * bf2f(qkv[((size_t)b * NT + tok[j]) * 2304 + 768 + h * 64 + lane]);
#pragma unroll
            for (int off = 32; off; off >>= 1) p += __shfl_xor(p, off);
            a[j] = p;
        }
        float mx = fmaxf(fmaxf(a[0], a[1]), fmaxf(a[2], a[3]));
        float e0 = expf(a[0] - mx), e1 = expf(a[1] - mx), e2 = expf(a[2] - mx), e3 = expf(a[3] - mx);
        float inv = 1.f / (e0 + e1 + e2 + e3);
        float v0 = bf2f(qkv[((size_t)b * NT + tok[0]) * 2304 + 1536 + h * 64 + lane]);
        float v1 = bf2f(qkv[((size_t)b * NT + tok[1]) * 2304 + 1536 + h * 64 + lane]);
        float v2 = bf2f(qkv[((size_t)b * NT + tok[2]) * 2304 + 1536 + h * 64 + lane]);
        float v3 = bf2f(qkv[((size_t)b * NT + tok[3]) * 2304 + 1536 + h * 64 + lane]);
        float o = (e0 * v0 + e1 * v1 + e2 * v2 + e3 * v3) * inv;
        Z[((size_t)b * NT + NGL + m) * CDIM + h * 64 + lane] = f2bf(o);
    }
}

extern "C" void kernel_launch(void* const* d_in, const int* in_sizes, int n_in,
                              void* d_out, int out_size, void* d_ws, size_t ws_size,
                              hipStream_t stream) {
    const float* x      = (const float*)d_in[0];
    const float* ps     = (const float*)d_in[1];
    const float* n1w    = (const float*)d_in[3];
    const float* n1b    = (const float*)d_in[4];
    const float* qkv_w  = (const float*)d_in[5];
    const float* proj_w = (const float*)d_in[6];
    const float* proj_b = (const float*)d_in[7];
    const float* n2w    = (const float*)d_in[8];
    const float* n2b    = (const float*)d_in[9];
    const float* fc1_w  = (const float*)d_in[10];
    const float* fc1_b  = (const float*)d_in[11];
    const float* fc2_w  = (const float*)d_in[12];
    const float* fc2_b  = (const float*)d_in[13];

    char* ws = (char*)d_ws;
    const int M = 32 * NT;  // 8352
    u16* hbuf  = (u16*)ws;                               // 12,828,672 B
    u16* qkvb  = (u16*)(ws + 12828672);                  // 38,486,016 B
    u16* Zb    = (u16*)(ws + 12828672 + 38486016);       // 12,828,672 B
    u16* Gb    = (u16*)(ws + 12828672);                  // 51,314,688 B (aliases qkv+Z, both dead)
    float* x1  = (float*)(ws + 64143360);                // 25,657,344 B
    u16* wq    = (u16*)(ws + 89800704);
    u16* wp    = wq + 2304 * 768;
    u16* w1    = wp + 768 * 768;
    u16* w2    = w1 + 3072 * 768;

    convk<<<(2304 * 768 / 4 + 255) / 256, 256, 0, stream>>>(qkv_w, wq, 2304 * 768 / 4);
    convk<<<(768 * 768 / 4 + 255) / 256, 256, 0, stream>>>(proj_w, wp, 768 * 768 / 4);
    convk<<<(3072 * 768 / 4 + 255) / 256, 256, 0, stream>>>(fc1_w, w1, 3072 * 768 / 4);
    convk<<<(768 * 3072 / 4 + 255) / 256, 256, 0, stream>>>(fc2_w, w2, 768 * 3072 / 4);

    ln_k<<<M, 256, 0, stream>>>(x, n1w, n1b, hbuf);
    gemm3<0><<<66 * 18, 256, 0, stream>>>(hbuf, wq, M, 2304, 768, 18, nullptr, nullptr, qkvb);
    attn_global_mfma<<<32 * NHEAD * 4, 256, 0, stream>>>(qkvb, Zb);
    attn_neigh<<<32 * 64, 64, 0, stream>>>(qkvb, ps, Zb);
    gemm3<1><<<66 * 6, 256, 0, stream>>>(Zb, wp, M, 768, 768, 6, proj_b, x, x1);
    ln_k<<<M, 256, 0, stream>>>(x1, n2w, n2b, hbuf);
    gemm3<2><<<66 * 24, 256, 0, stream>>>(hbuf, w1, M, 3072, 768, 24, fc1_b, nullptr, Gb);
    gemm3<1><<<66 * 6, 256, 0, stream>>>(Gb, w2, M, 768, 3072, 6, fc2_b, x1, (float*)d_out);
}

// Round 5
// 309.126 us; speedup vs baseline: 1.0436x; 1.0436x over previous
//
#include <hip/hip_runtime.h>

typedef unsigned short u16;
typedef unsigned int u32;
typedef u16 u16x8 __attribute__((ext_vector_type(8)));
typedef u16 u16x4 __attribute__((ext_vector_type(4)));
typedef float f32x4 __attribute__((ext_vector_type(4)));
typedef __bf16 bf16x8 __attribute__((ext_vector_type(8)));

#define NHEAD 12
#define NT 261
#define NGL 197
#define CDIM 768
#define KT 14
#define PS_STRIDE 232
#define VT_STRIDE 232

__device__ __forceinline__ float bf2f(u16 u) {
    u32 x = ((u32)u) << 16;
    float f;
    __builtin_memcpy(&f, &x, 4);
    return f;
}
__device__ __forceinline__ u16 f2bf(float f) {
    u32 x;
    __builtin_memcpy(&x, &f, 4);
    x = (x + 0x7fffu + ((x >> 16) & 1u)) >> 16;
    return (u16)x;
}

#define GLD_LDS16(g, l) \
    __builtin_amdgcn_global_load_lds((const __attribute__((address_space(1))) void*)(g), \
                                     (__attribute__((address_space(3))) void*)(l), 16, 0, 0)
#define WAITV(n) asm volatile("s_waitcnt vmcnt(" #n ")" ::: "memory")
#define BARM() asm volatile("s_barrier" ::: "memory")

// ---------------- fp32 -> bf16 weight conversion (all 4 weights, one launch) ----------------
struct CvArgs {
    const float* in[4];
    u16* out[4];
    int n4[4];
};
__global__ __launch_bounds__(256) void convk4(CvArgs a) {
    int y = blockIdx.y;
    const float* in = a.in[y];
    u16* out = a.out[y];
    int n4 = a.n4[y];
    int i = blockIdx.x * 256 + threadIdx.x;
    if (i >= n4) return;
    float4 v = ((const float4*)in)[i];
    u16x4 o;
    o[0] = f2bf(v.x); o[1] = f2bf(v.y); o[2] = f2bf(v.z); o[3] = f2bf(v.w);
    ((u16x4*)out)[i] = o;
}

// ---------------- LayerNorm (row of 768) -> bf16 ----------------
__global__ __launch_bounds__(256) void ln_k(const float* __restrict__ in, const float* __restrict__ w,
                                            const float* __restrict__ bia, u16* __restrict__ out) {
    int row = blockIdx.x;
    int tid = threadIdx.x;
    const float* r = in + (size_t)row * CDIM;
    float v0 = r[tid], v1 = r[tid + 256], v2 = r[tid + 512];
    float s = v0 + v1 + v2;
    float ss = v0 * v0 + v1 * v1 + v2 * v2;
#pragma unroll
    for (int off = 32; off; off >>= 1) {
        s += __shfl_xor(s, off);
        ss += __shfl_xor(ss, off);
    }
    __shared__ float ls[4], lss[4];
    int wv = tid >> 6;
    if ((tid & 63) == 0) { ls[wv] = s; lss[wv] = ss; }
    __syncthreads();
    s = ls[0] + ls[1] + ls[2] + ls[3];
    ss = lss[0] + lss[1] + lss[2] + lss[3];
    float mu = s * (1.f / 768.f);
    float var = ss * (1.f / 768.f) - mu * mu;
    float inv = rsqrtf(var + 1e-5f);
    u16* o = out + (size_t)row * CDIM;
    o[tid]       = f2bf((v0 - mu) * inv * w[tid]       + bia[tid]);
    o[tid + 256] = f2bf((v1 - mu) * inv * w[tid + 256] + bia[tid + 256]);
    o[tid + 512] = f2bf((v2 - mu) * inv * w[tid + 512] + bia[tid + 512]);
}

// ---------------- big-tile pipelined MFMA GEMM: C[m,n] = sum_k A[m,k]*B[n,k] ----------------
// TM x 128 tile, BK=64, TM*2 threads (8 or 4 waves of 64x64 output each).
// 2 LDS slots; stage(t+1) issued at tile-t start; counted vmcnt keeps t+1 in flight.
// 16B-slot XOR swizzle (slot ^= row&7) via pre-swizzled global SOURCE (linear gld_lds dest),
// re-applied on fragment reads -> ~2-way banks (free).
// EPI: 0 = plain -> bf16; 1 = +bias +residual(fp32) -> fp32; 2 = +bias +gelu(tanh) -> bf16
template <int EPI, int TM>
__global__ __launch_bounds__(TM * 2, 2) void gemm4(const u16* __restrict__ A, const u16* __restrict__ Bw,
                                                   int M, int N, int K, int nbn,
                                                   const float* __restrict__ bias,
                                                   const float* __restrict__ resid, void* __restrict__ outp) {
    constexpr int THREADS = TM * 2;
    constexpr int ROWSP = THREADS / 8;      // rows covered per staging issue
    constexpr int NBI = 128 / ROWSP;        // staging issues for B (A is always 4)
    constexpr int SLOT = TM * 64 + 8192;    // u16 per slot (A tile + B tile)
    __shared__ __align__(16) u16 sm[2 * SLOT];
    const int tid = threadIdx.x;
    // bijective XCD swizzle (m204)
    const int nwg = gridDim.x;
    const int q = nwg >> 3, r = nwg & 7;
    const int xcd = blockIdx.x & 7, within = blockIdx.x >> 3;
    const int id2 = (xcd < r ? xcd * (q + 1) : r * (q + 1) + (xcd - r) * q) + within;
    const int bm = id2 / nbn, bn = id2 % nbn;
    const int lane = tid & 63, wv = tid >> 6;
    const int wr = wv >> 1, wc = wv & 1;
    const int l15 = lane & 15, lg = lane >> 4;
    const int arow0 = bm * TM, brow0 = bn * 128;
    const int nt = K >> 6;

    // staging: thread covers LDS u16 [issue*ROWSP*64 + tid*8]; source col pre-swizzled
    const int srow = tid >> 3;
    const int sk = ((tid & 7) ^ (srow & 7)) * 8;    // u16 col in [0,64)
    const u16* gA[4];
    const u16* gB[NBI];
#pragma unroll
    for (int i = 0; i < 4; ++i) {
        int ar = arow0 + i * ROWSP + srow;
        if (ar >= M) ar = M - 1;
        gA[i] = A + (size_t)ar * K + sk;
    }
#pragma unroll
    for (int j = 0; j < NBI; ++j)
        gB[j] = Bw + (size_t)(brow0 + j * ROWSP + srow) * K + sk;

    auto STAGE = [&](int tt) {
        u16* sb = sm + (tt & 1) * SLOT;
        const size_t ko = (size_t)tt * 64;
#pragma unroll
        for (int i = 0; i < 4; ++i) GLD_LDS16(gA[i] + ko, sb + i * (ROWSP * 64) + tid * 8);
#pragma unroll
        for (int j = 0; j < NBI; ++j) GLD_LDS16(gB[j] + ko, sb + TM * 64 + j * (ROWSP * 64) + tid * 8);
    };

    f32x4 acc[4][4] = {};
    const int xb = l15 & 7;                 // row-XOR term for fragment reads

    STAGE(0);
    for (int t = 0; t < nt; ++t) {
        if (t + 1 < nt) {
            STAGE(t + 1);
            if constexpr (TM == 256) { WAITV(6); } else { WAITV(8); }
        } else {
            WAITV(0);
        }
        BARM();
        const u16* sb = sm + (t & 1) * SLOT;
        bf16x8 af[4][2], bq[4][2];
#pragma unroll
        for (int mi = 0; mi < 4; ++mi)
#pragma unroll
            for (int kk = 0; kk < 2; ++kk)
                af[mi][kk] = *(const bf16x8*)(sb + (wr * 64 + mi * 16 + l15) * 64 + (((kk << 2) | lg) ^ xb) * 8);
#pragma unroll
        for (int ni = 0; ni < 4; ++ni)
#pragma unroll
            for (int kk = 0; kk < 2; ++kk)
                bq[ni][kk] = *(const bf16x8*)(sb + TM * 64 + (wc * 64 + ni * 16 + l15) * 64 + (((kk << 2) | lg) ^ xb) * 8);
#pragma unroll
        for (int mi = 0; mi < 4; ++mi)
#pragma unroll
            for (int ni = 0; ni < 4; ++ni) {
                acc[mi][ni] = __builtin_amdgcn_mfma_f32_16x16x32_bf16(af[mi][0], bq[ni][0], acc[mi][ni], 0, 0, 0);
                acc[mi][ni] = __builtin_amdgcn_mfma_f32_16x16x32_bf16(af[mi][1], bq[ni][1], acc[mi][ni], 0, 0, 0);
            }
        if (t + 2 < nt) BARM();             // release slot(t&1) before stage(t+2) writes it
    }

#pragma unroll
    for (int mi = 0; mi < 4; ++mi) {
        int row0 = arow0 + wr * 64 + mi * 16 + lg * 4;
#pragma unroll
        for (int ni = 0; ni < 4; ++ni) {
            int col = brow0 + wc * 64 + ni * 16 + l15;
            float bb = (EPI == 0) ? 0.f : bias[col];
#pragma unroll
            for (int rr = 0; rr < 4; ++rr) {
                int row = row0 + rr;
                if (row < M) {
                    float v = acc[mi][ni][rr] + bb;
                    if (EPI == 2) {
                        float z = v + 0.044715f * v * v * v;
                        v = v / (1.f + __expf(-1.5957691216f * z));   // tanh-gelu (dev ~3e-3)
                    }
                    if (EPI == 1) {
                        v += resid[(size_t)row * N + col];
                        ((float*)outp)[(size_t)row * N + col] = v;
                    } else {
                        ((u16*)outp)[(size_t)row * N + col] = f2bf(v);
                    }
                }
            }
        }
    }
}

// ---------------- Global attention via MFMA ----------------
__global__ __launch_bounds__(256) void attn_global_mfma(const u16* __restrict__ qkv, u16* __restrict__ Z) {
    __shared__ __align__(16) u16 lds0[4 * 16 * PS_STRIDE];
    __shared__ __align__(16) u16 Vt[64 * VT_STRIDE];
    const int tid = threadIdx.x;
    const int blk = blockIdx.x;
    const int qt = blk & 3;
    const int bh = blk >> 2;
    const int h = bh % NHEAD, b = bh / NHEAD;
    const int lane = tid & 63, wv = tid >> 6;
    const int l15 = lane & 15, lg = lane >> 4;
    const u16* base = qkv + (size_t)b * NT * 2304;

    for (int c = tid; c < 224 * 8; c += 256) {
        int row = c >> 3, ch = c & 7;
        u16x8 v = {};
        if (row < NGL) v = *(const u16x8*)(base + (size_t)row * 2304 + 768 + h * 64 + ch * 8);
        int byte = row * 128 + ((ch * 16) ^ ((row & 7) << 4));
        *(u16x8*)((char*)lds0 + byte) = v;
    }
    for (int c = tid; c < 112 * 8; c += 256) {
        int mp = c >> 3, dch = c & 7;
        int m0 = mp * 2;
        u16x8 a0 = {}, a1 = {};
        if (m0 < NGL)     a0 = *(const u16x8*)(base + (size_t)m0 * 2304 + 1536 + h * 64 + dch * 8);
        if (m0 + 1 < NGL) a1 = *(const u16x8*)(base + (size_t)(m0 + 1) * 2304 + 1536 + h * 64 + dch * 8);
#pragma unroll
        for (int j = 0; j < 8; ++j) {
            u32 pk = (u32)a0[j] | ((u32)a1[j] << 16);
            *(u32*)((char*)Vt + (size_t)(dch * 8 + j) * (VT_STRIDE * 2) + m0 * 2) = pk;
        }
    }
    const int q0 = qt * 64 + wv * 16;
    int qrow = q0 + l15; if (qrow > NGL - 1) qrow = NGL - 1;
    bf16x8 aq0 = *(const bf16x8*)(base + (size_t)qrow * 2304 + h * 64 + lg * 8);
    bf16x8 aq1 = *(const bf16x8*)(base + (size_t)qrow * 2304 + h * 64 + 32 + lg * 8);
    __syncthreads();

    f32x4 s[KT];
    const int sw = (l15 & 7) << 4;
#pragma unroll
    for (int t = 0; t < KT; ++t) {
        const char* krow = (const char*)lds0 + (t * 16 + l15) * 128;
        bf16x8 bk0 = *(const bf16x8*)(krow + ((lg * 16) ^ sw));
        bf16x8 bk1 = *(const bf16x8*)(krow + ((64 + lg * 16) ^ sw));
        f32x4 acc = {};
        acc = __builtin_amdgcn_mfma_f32_16x16x32_bf16(aq0, bk0, acc, 0, 0, 0);
        acc = __builtin_amdgcn_mfma_f32_16x16x32_bf16(aq1, bk1, acc, 0, 0, 0);
        s[t] = acc * 0.125f;
    }
    float mx[4] = {-1e30f, -1e30f, -1e30f, -1e30f};
#pragma unroll
    for (int t = 0; t < KT; ++t)
#pragma unroll
        for (int r = 0; r < 4; ++r) mx[r] = fmaxf(mx[r], s[t][r]);
#pragma unroll
    for (int off = 1; off < 16; off <<= 1)
#pragma unroll
        for (int r = 0; r < 4; ++r) mx[r] = fmaxf(mx[r], __shfl_xor(mx[r], off));
    float sum[4] = {};
#pragma unroll
    for (int t = 0; t < KT; ++t) {
        bool valid = (t * 16 + l15) < NGL;
#pragma unroll
        for (int r = 0; r < 4; ++r) {
            float e = valid ? __expf(s[t][r] - mx[r]) : 0.f;
            s[t][r] = e;
            sum[r] += e;
        }
    }
#pragma unroll
    for (int off = 1; off < 16; off <<= 1)
#pragma unroll
        for (int r = 0; r < 4; ++r) sum[r] += __shfl_xor(sum[r], off);
    float inv[4];
#pragma unroll
    for (int r = 0; r < 4; ++r) inv[r] = 1.f / sum[r];

    __syncthreads();
    u16* Pw = lds0 + wv * 16 * PS_STRIDE;
#pragma unroll
    for (int t = 0; t < KT; ++t)
#pragma unroll
        for (int r = 0; r < 4; ++r)
            Pw[(4 * lg + r) * PS_STRIDE + t * 16 + l15] = f2bf(s[t][r] * inv[r]);

    f32x4 o[4] = {};
#pragma unroll
    for (int ks = 0; ks < 7; ++ks) {
        bf16x8 pa = *(const bf16x8*)(Pw + l15 * PS_STRIDE + ks * 32 + lg * 8);
#pragma unroll
        for (int dt = 0; dt < 4; ++dt) {
            bf16x8 bv = *(const bf16x8*)((const char*)Vt + (size_t)(dt * 16 + l15) * (VT_STRIDE * 2) + ks * 64 + lg * 16);
            o[dt] = __builtin_amdgcn_mfma_f32_16x16x32_bf16(pa, bv, o[dt], 0, 0, 0);
        }
    }
#pragma unroll
    for (int dt = 0; dt < 4; ++dt)
#pragma unroll
        for (int r = 0; r < 4; ++r) {
            int q = q0 + 4 * lg + r;
            if (q < NGL) Z[((size_t)b * NT + q) * CDIM + h * 64 + dt * 16 + l15] = f2bf(o[dt][r]);
        }
}

// ---------------- Neighborhood attention ----------------
__global__ __launch_bounds__(64) void attn_neigh(const u16* __restrict__ qkv, const float* __restrict__ ps,
                                                 u16* __restrict__ Z) {
    int blk = blockIdx.x;
    int b = blk >> 6, m = blk & 63;
    int lane = threadIdx.x;
    float px = ps[((size_t)b * 64 + m) * 2 + 0] * (1.f / 16.f);
    float py = ps[((size_t)b * 64 + m) * 2 + 1] * (1.f / 16.f);
    int c0 = min(max((int)floorf(px), 0), 13);
    int c1 = min(max((int)ceilf(px), 0), 13);
    int r0 = min(max((int)floorf(py), 0), 13);
    int r1 = min(max((int)ceilf(py), 0), 13);
    int tok[4];
    tok[0] = 1 + r0 * 14 + c0;
    tok[1] = 1 + r1 * 14 + c0;
    tok[2] = 1 + r0 * 14 + c1;
    tok[3] = 1 + r1 * 14 + c1;
    const size_t rowq = ((size_t)b * NT + NGL + m) * 2304;
#pragma unroll 1
    for (int h = 0; h < NHEAD; ++h) {
        float qv = bf2f(qkv[rowq + h * 64 + lane]);
        float a[4];
#pragma unroll
        for (int j = 0; j < 4; ++j) {
            float p = qv * bf2f(qkv[((size_t)b * NT + tok[j]) * 2304 + 768 + h * 64 + lane]);
#pragma unroll
            for (int off = 32; off; off >>= 1) p += __shfl_xor(p, off);
            a[j] = p;
        }
        float mx = fmaxf(fmaxf(a[0], a[1]), fmaxf(a[2], a[3]));
        float e0 = expf(a[0] - mx), e1 = expf(a[1] - mx), e2 = expf(a[2] - mx), e3 = expf(a[3] - mx);
        float inv = 1.f / (e0 + e1 + e2 + e3);
        float v0 = bf2f(qkv[((size_t)b * NT + tok[0]) * 2304 + 1536 + h * 64 + lane]);
        float v1 = bf2f(qkv[((size_t)b * NT + tok[1]) * 2304 + 1536 + h * 64 + lane]);
        float v2 = bf2f(qkv[((size_t)b * NT + tok[2]) * 2304 + 1536 + h * 64 + lane]);
        float v3 = bf2f(qkv[((size_t)b * NT + tok[3]) * 2304 + 1536 + h * 64 + lane]);
        float o = (e0 * v0 + e1 * v1 + e2 * v2 + e3 * v3) * inv;
        Z[((size_t)b * NT + NGL + m) * CDIM + h * 64 + lane] = f2bf(o);
    }
}

extern "C" void kernel_launch(void* const* d_in, const int* in_sizes, int n_in,
                              void* d_out, int out_size, void* d_ws, size_t ws_size,
                              hipStream_t stream) {
    const float* x      = (const float*)d_in[0];
    const float* ps     = (const float*)d_in[1];
    const float* n1w    = (const float*)d_in[3];
    const float* n1b    = (const float*)d_in[4];
    const float* qkv_w  = (const float*)d_in[5];
    const float* proj_w = (const float*)d_in[6];
    const float* proj_b = (const float*)d_in[7];
    const float* n2w    = (const float*)d_in[8];
    const float* n2b    = (const float*)d_in[9];
    const float* fc1_w  = (const float*)d_in[10];
    const float* fc1_b  = (const float*)d_in[11];
    const float* fc2_w  = (const float*)d_in[12];
    const float* fc2_b  = (const float*)d_in[13];

    char* ws = (char*)d_ws;
    const int M = 32 * NT;  // 8352
    u16* hbuf  = (u16*)ws;                               // 12,828,672 B
    u16* qkvb  = (u16*)(ws + 12828672);                  // 38,486,016 B
    u16* Zb    = (u16*)(ws + 12828672 + 38486016);       // 12,828,672 B
    u16* Gb    = (u16*)(ws + 12828672);                  // 51,314,688 B (aliases qkv+Z, both dead)
    float* x1  = (float*)(ws + 64143360);                // 25,657,344 B
    u16* wq    = (u16*)(ws + 89800704);
    u16* wp    = wq + 2304 * 768;
    u16* w1    = wp + 768 * 768;
    u16* w2    = w1 + 3072 * 768;

    CvArgs cv;
    cv.in[0] = qkv_w;  cv.out[0] = wq; cv.n4[0] = 2304 * 768 / 4;
    cv.in[1] = proj_w; cv.out[1] = wp; cv.n4[1] = 768 * 768 / 4;
    cv.in[2] = fc1_w;  cv.out[2] = w1; cv.n4[2] = 3072 * 768 / 4;
    cv.in[3] = fc2_w;  cv.out[3] = w2; cv.n4[3] = 768 * 3072 / 4;
    convk4<<<dim3((3072 * 768 / 4 + 255) / 256, 4), 256, 0, stream>>>(cv);

    ln_k<<<M, 256, 0, stream>>>(x, n1w, n1b, hbuf);
    gemm4<0, 256><<<33 * 18, 512, 0, stream>>>(hbuf, wq, M, 2304, 768, 18, nullptr, nullptr, qkvb);
    attn_global_mfma<<<32 * NHEAD * 4, 256, 0, stream>>>(qkvb, Zb);
    attn_neigh<<<32 * 64, 64, 0, stream>>>(qkvb, ps, Zb);
    gemm4<1, 128><<<66 * 6, 256, 0, stream>>>(Zb, wp, M, 768, 768, 6, proj_b, x, x1);
    ln_k<<<M, 256, 0, stream>>>(x1, n2w, n2b, hbuf);
    gemm4<2, 256><<<33 * 24, 512, 0, stream>>>(hbuf, w1, M, 3072, 768, 24, fc1_b, nullptr, Gb);
    gemm4<1, 128><<<66 * 6, 256, 0, stream>>>(Gb, w2, M, 768, 3072, 6, fc2_b, x1, (float*)d_out);
}

// Round 6
// 308.680 us; speedup vs baseline: 1.0451x; 1.0014x over previous
//
#include <hip/hip_runtime.h>

typedef unsigned short u16;
typedef unsigned int u32;
typedef u16 u16x8 __attribute__((ext_vector_type(8)));
typedef u16 u16x4 __attribute__((ext_vector_type(4)));
typedef float f32x4 __attribute__((ext_vector_type(4)));
typedef __bf16 bf16x8 __attribute__((ext_vector_type(8)));

#define NHEAD 12
#define NT 261
#define NGL 197
#define CDIM 768
#define KT 14
#define PS_STRIDE 232
#define VT_STRIDE 232

__device__ __forceinline__ float bf2f(u16 u) {
    u32 x = ((u32)u) << 16;
    float f;
    __builtin_memcpy(&f, &x, 4);
    return f;
}
__device__ __forceinline__ u16 f2bf(float f) {
    u32 x;
    __builtin_memcpy(&x, &f, 4);
    x = (x + 0x7fffu + ((x >> 16) & 1u)) >> 16;
    return (u16)x;
}

#define GLD_LDS16(g, l) \
    __builtin_amdgcn_global_load_lds((const __attribute__((address_space(1))) void*)(g), \
                                     (__attribute__((address_space(3))) void*)(l), 16, 0, 0)
#define WAITV(n) asm volatile("s_waitcnt vmcnt(" #n ")" ::: "memory")
#define BARM() asm volatile("s_barrier" ::: "memory")

// ---------------- fp32 -> bf16 weight conversion (all 4 weights, one launch) ----------------
struct CvArgs {
    const float* in[4];
    u16* out[4];
    int n4[4];
};
__global__ __launch_bounds__(256) void convk4(CvArgs a) {
    int y = blockIdx.y;
    const float* in = a.in[y];
    u16* out = a.out[y];
    int n4 = a.n4[y];
    int i = blockIdx.x * 256 + threadIdx.x;
    if (i >= n4) return;
    float4 v = ((const float4*)in)[i];
    u16x4 o;
    o[0] = f2bf(v.x); o[1] = f2bf(v.y); o[2] = f2bf(v.z); o[3] = f2bf(v.w);
    ((u16x4*)out)[i] = o;
}

// ---------------- LayerNorm (row of 768) -> bf16 ----------------
__global__ __launch_bounds__(256) void ln_k(const float* __restrict__ in, const float* __restrict__ w,
                                            const float* __restrict__ bia, u16* __restrict__ out) {
    int row = blockIdx.x;
    int tid = threadIdx.x;
    const float* r = in + (size_t)row * CDIM;
    float v0 = r[tid], v1 = r[tid + 256], v2 = r[tid + 512];
    float s = v0 + v1 + v2;
    float ss = v0 * v0 + v1 * v1 + v2 * v2;
#pragma unroll
    for (int off = 32; off; off >>= 1) {
        s += __shfl_xor(s, off);
        ss += __shfl_xor(ss, off);
    }
    __shared__ float ls[4], lss[4];
    int wv = tid >> 6;
    if ((tid & 63) == 0) { ls[wv] = s; lss[wv] = ss; }
    __syncthreads();
    s = ls[0] + ls[1] + ls[2] + ls[3];
    ss = lss[0] + lss[1] + lss[2] + lss[3];
    float mu = s * (1.f / 768.f);
    float var = ss * (1.f / 768.f) - mu * mu;
    float inv = rsqrtf(var + 1e-5f);
    u16* o = out + (size_t)row * CDIM;
    o[tid]       = f2bf((v0 - mu) * inv * w[tid]       + bia[tid]);
    o[tid + 256] = f2bf((v1 - mu) * inv * w[tid + 256] + bia[tid + 256]);
    o[tid + 512] = f2bf((v2 - mu) * inv * w[tid + 512] + bia[tid + 512]);
}

// ---------------- 256x256 MFMA GEMM, 128x64 wave tiles: C[m,n] = sum_k A[m,k]*B[n,k] ----------
// 512 threads = 8 waves (2 row-groups x 4 col-groups); wave tile 128x64 (acc[8][4]).
// BK=64, 2 LDS slots (128 KiB), stage(t+1) at tile-t start, counted vmcnt(8), 2 barriers/tile.
// 16B-slot involution swizzle (slot ^= row&7) via pre-swizzled global source + same XOR on reads.
// EPI: 0 = plain -> bf16; 2 = +bias +gelu(tanh) -> bf16
template <int EPI>
__global__ __launch_bounds__(512, 2) void gemm5(const u16* __restrict__ A, const u16* __restrict__ Bw,
                                                int M, int N, int K, int nbn,
                                                const float* __restrict__ bias,
                                                void* __restrict__ outp) {
    __shared__ __align__(16) u16 sm[2][32768];   // [slot][A 16384 | B 16384] = 128 KiB
    const int tid = threadIdx.x;
    const int nwg = gridDim.x;
    const int q = nwg >> 3, r = nwg & 7;
    const int xcd = blockIdx.x & 7, within = blockIdx.x >> 3;
    const int id2 = (xcd < r ? xcd * (q + 1) : r * (q + 1) + (xcd - r) * q) + within;
    const int bm = id2 / nbn, bn = id2 % nbn;
    const int lane = tid & 63, wv = tid >> 6;
    const int wr = wv >> 2, wc = wv & 3;
    const int l15 = lane & 15, lg = lane >> 4;
    const int arow0 = bm * 256, brow0 = bn * 256;
    const int nt = K >> 6;

    // staging: 4 issues per operand; issue i covers rows i*64+srow; source col pre-swizzled
    const int srow = tid >> 3;
    const int sk = ((tid & 7) ^ (srow & 7)) * 8;
    const u16* gA[4];
    const u16* gB[4];
#pragma unroll
    for (int i = 0; i < 4; ++i) {
        int ar = arow0 + i * 64 + srow;
        if (ar >= M) ar = M - 1;
        gA[i] = A + (size_t)ar * K + sk;
        gB[i] = Bw + (size_t)(brow0 + i * 64 + srow) * K + sk;
    }

    auto STAGE = [&](int tt) {
        u16* sb = sm[tt & 1];
        const size_t ko = (size_t)tt * 64;
#pragma unroll
        for (int i = 0; i < 4; ++i) GLD_LDS16(gA[i] + ko, sb + i * 4096 + tid * 8);
#pragma unroll
        for (int i = 0; i < 4; ++i) GLD_LDS16(gB[i] + ko, sb + 16384 + i * 4096 + tid * 8);
    };

    f32x4 acc[8][4] = {};
    const int xb = l15 & 7;

    STAGE(0);
    for (int t = 0; t < nt; ++t) {
        if (t + 1 < nt) {
            STAGE(t + 1);
            WAITV(8);                        // stage(t) landed; stage(t+1)'s 8 stay in flight
        } else {
            WAITV(0);
        }
        BARM();
        const u16* sb = sm[t & 1];
        bf16x8 bq[4][2];
#pragma unroll
        for (int ni = 0; ni < 4; ++ni)
#pragma unroll
            for (int kk = 0; kk < 2; ++kk)
                bq[ni][kk] = *(const bf16x8*)(sb + 16384 + (wc * 64 + ni * 16 + l15) * 64 + (((kk << 2) | lg) ^ xb) * 8);
#pragma unroll
        for (int mi = 0; mi < 8; ++mi) {
            const u16* arow = sb + (wr * 128 + mi * 16 + l15) * 64;
            bf16x8 a0 = *(const bf16x8*)(arow + ((lg ^ xb) * 8));
            bf16x8 a1 = *(const bf16x8*)(arow + (((4 | lg) ^ xb) * 8));
#pragma unroll
            for (int ni = 0; ni < 4; ++ni) {
                acc[mi][ni] = __builtin_amdgcn_mfma_f32_16x16x32_bf16(a0, bq[ni][0], acc[mi][ni], 0, 0, 0);
                acc[mi][ni] = __builtin_amdgcn_mfma_f32_16x16x32_bf16(a1, bq[ni][1], acc[mi][ni], 0, 0, 0);
            }
        }
        if (t + 2 < nt) BARM();              // release slot(t&1) before stage(t+2) overwrites it
    }

#pragma unroll
    for (int mi = 0; mi < 8; ++mi) {
        int row0 = arow0 + wr * 128 + mi * 16 + lg * 4;
#pragma unroll
        for (int ni = 0; ni < 4; ++ni) {
            int col = brow0 + wc * 64 + ni * 16 + l15;
            float bb = (EPI == 0) ? 0.f : bias[col];
#pragma unroll
            for (int rr = 0; rr < 4; ++rr) {
                int row = row0 + rr;
                if (row < M) {
                    float v = acc[mi][ni][rr] + bb;
                    if (EPI == 2) {
                        float z = v + 0.044715f * v * v * v;
                        v = v / (1.f + __expf(-1.5957691216f * z));
                    }
                    ((u16*)outp)[(size_t)row * N + col] = f2bf(v);
                }
            }
        }
    }
}

// ---------------- 128x128 pipelined GEMM (narrow-N ops): proven gemm4<128> ----------------
// EPI: 1 = +bias +residual(fp32) -> fp32
template <int EPI>
__global__ __launch_bounds__(256, 2) void gemm4n(const u16* __restrict__ A, const u16* __restrict__ Bw,
                                                 int M, int N, int K, int nbn,
                                                 const float* __restrict__ bias,
                                                 const float* __restrict__ resid, void* __restrict__ outp) {
    constexpr int SLOT = 128 * 64 + 8192;
    __shared__ __align__(16) u16 sm[2 * SLOT];
    const int tid = threadIdx.x;
    const int nwg = gridDim.x;
    const int q = nwg >> 3, r = nwg & 7;
    const int xcd = blockIdx.x & 7, within = blockIdx.x >> 3;
    const int id2 = (xcd < r ? xcd * (q + 1) : r * (q + 1) + (xcd - r) * q) + within;
    const int bm = id2 / nbn, bn = id2 % nbn;
    const int lane = tid & 63, wv = tid >> 6;
    const int wr = wv >> 1, wc = wv & 1;
    const int l15 = lane & 15, lg = lane >> 4;
    const int arow0 = bm * 128, brow0 = bn * 128;
    const int nt = K >> 6;

    const int srow = tid >> 3;
    const int sk = ((tid & 7) ^ (srow & 7)) * 8;
    const u16* gA[4];
    const u16* gB[4];
#pragma unroll
    for (int i = 0; i < 4; ++i) {
        int ar = arow0 + i * 32 + srow;
        if (ar >= M) ar = M - 1;
        gA[i] = A + (size_t)ar * K + sk;
        gB[i] = Bw + (size_t)(brow0 + i * 32 + srow) * K + sk;
    }

    auto STAGE = [&](int tt) {
        u16* sb = sm + (tt & 1) * SLOT;
        const size_t ko = (size_t)tt * 64;
#pragma unroll
        for (int i = 0; i < 4; ++i) GLD_LDS16(gA[i] + ko, sb + i * 2048 + tid * 8);
#pragma unroll
        for (int i = 0; i < 4; ++i) GLD_LDS16(gB[i] + ko, sb + 8192 + i * 2048 + tid * 8);
    };

    f32x4 acc[4][4] = {};
    const int xb = l15 & 7;

    STAGE(0);
    for (int t = 0; t < nt; ++t) {
        if (t + 1 < nt) {
            STAGE(t + 1);
            WAITV(8);
        } else {
            WAITV(0);
        }
        BARM();
        const u16* sb = sm + (t & 1) * SLOT;
        bf16x8 af[4][2], bq[4][2];
#pragma unroll
        for (int mi = 0; mi < 4; ++mi)
#pragma unroll
            for (int kk = 0; kk < 2; ++kk)
                af[mi][kk] = *(const bf16x8*)(sb + (wr * 64 + mi * 16 + l15) * 64 + (((kk << 2) | lg) ^ xb) * 8);
#pragma unroll
        for (int ni = 0; ni < 4; ++ni)
#pragma unroll
            for (int kk = 0; kk < 2; ++kk)
                bq[ni][kk] = *(const bf16x8*)(sb + 8192 + (wc * 64 + ni * 16 + l15) * 64 + (((kk << 2) | lg) ^ xb) * 8);
#pragma unroll
        for (int mi = 0; mi < 4; ++mi)
#pragma unroll
            for (int ni = 0; ni < 4; ++ni) {
                acc[mi][ni] = __builtin_amdgcn_mfma_f32_16x16x32_bf16(af[mi][0], bq[ni][0], acc[mi][ni], 0, 0, 0);
                acc[mi][ni] = __builtin_amdgcn_mfma_f32_16x16x32_bf16(af[mi][1], bq[ni][1], acc[mi][ni], 0, 0, 0);
            }
        if (t + 2 < nt) BARM();
    }

#pragma unroll
    for (int mi = 0; mi < 4; ++mi) {
        int row0 = arow0 + wr * 64 + mi * 16 + lg * 4;
#pragma unroll
        for (int ni = 0; ni < 4; ++ni) {
            int col = brow0 + wc * 64 + ni * 16 + l15;
            float bb = bias[col];
#pragma unroll
            for (int rr = 0; rr < 4; ++rr) {
                int row = row0 + rr;
                if (row < M) {
                    float v = acc[mi][ni][rr] + bb + resid[(size_t)row * N + col];
                    ((float*)outp)[(size_t)row * N + col] = v;
                }
            }
        }
    }
}

// ---------------- Global attention via MFMA ----------------
__global__ __launch_bounds__(256) void attn_global_mfma(const u16* __restrict__ qkv, u16* __restrict__ Z) {
    __shared__ __align__(16) u16 lds0[4 * 16 * PS_STRIDE];
    __shared__ __align__(16) u16 Vt[64 * VT_STRIDE];
    const int tid = threadIdx.x;
    const int blk = blockIdx.x;
    const int qt = blk & 3;
    const int bh = blk >> 2;
    const int h = bh % NHEAD, b = bh / NHEAD;
    const int lane = tid & 63, wv = tid >> 6;
    const int l15 = lane & 15, lg = lane >> 4;
    const u16* base = qkv + (size_t)b * NT * 2304;

    for (int c = tid; c < 224 * 8; c += 256) {
        int row = c >> 3, ch = c & 7;
        u16x8 v = {};
        if (row < NGL) v = *(const u16x8*)(base + (size_t)row * 2304 + 768 + h * 64 + ch * 8);
        int byte = row * 128 + ((ch * 16) ^ ((row & 7) << 4));
        *(u16x8*)((char*)lds0 + byte) = v;
    }
    for (int c = tid; c < 112 * 8; c += 256) {
        int mp = c >> 3, dch = c & 7;
        int m0 = mp * 2;
        u16x8 a0 = {}, a1 = {};
        if (m0 < NGL)     a0 = *(const u16x8*)(base + (size_t)m0 * 2304 + 1536 + h * 64 + dch * 8);
        if (m0 + 1 < NGL) a1 = *(const u16x8*)(base + (size_t)(m0 + 1) * 2304 + 1536 + h * 64 + dch * 8);
#pragma unroll
        for (int j = 0; j < 8; ++j) {
            u32 pk = (u32)a0[j] | ((u32)a1[j] << 16);
            *(u32*)((char*)Vt + (size_t)(dch * 8 + j) * (VT_STRIDE * 2) + m0 * 2) = pk;
        }
    }
    const int q0 = qt * 64 + wv * 16;
    int qrow = q0 + l15; if (qrow > NGL - 1) qrow = NGL - 1;
    bf16x8 aq0 = *(const bf16x8*)(base + (size_t)qrow * 2304 + h * 64 + lg * 8);
    bf16x8 aq1 = *(const bf16x8*)(base + (size_t)qrow * 2304 + h * 64 + 32 + lg * 8);
    __syncthreads();

    f32x4 s[KT];
    const int sw = (l15 & 7) << 4;
#pragma unroll
    for (int t = 0; t < KT; ++t) {
        const char* krow = (const char*)lds0 + (t * 16 + l15) * 128;
        bf16x8 bk0 = *(const bf16x8*)(krow + ((lg * 16) ^ sw));
        bf16x8 bk1 = *(const bf16x8*)(krow + ((64 + lg * 16) ^ sw));
        f32x4 acc = {};
        acc = __builtin_amdgcn_mfma_f32_16x16x32_bf16(aq0, bk0, acc, 0, 0, 0);
        acc = __builtin_amdgcn_mfma_f32_16x16x32_bf16(aq1, bk1, acc, 0, 0, 0);
        s[t] = acc * 0.125f;
    }
    float mx[4] = {-1e30f, -1e30f, -1e30f, -1e30f};
#pragma unroll
    for (int t = 0; t < KT; ++t)
#pragma unroll
        for (int r = 0; r < 4; ++r) mx[r] = fmaxf(mx[r], s[t][r]);
#pragma unroll
    for (int off = 1; off < 16; off <<= 1)
#pragma unroll
        for (int r = 0; r < 4; ++r) mx[r] = fmaxf(mx[r], __shfl_xor(mx[r], off));
    float sum[4] = {};
#pragma unroll
    for (int t = 0; t < KT; ++t) {
        bool valid = (t * 16 + l15) < NGL;
#pragma unroll
        for (int r = 0; r < 4; ++r) {
            float e = valid ? __expf(s[t][r] - mx[r]) : 0.f;
            s[t][r] = e;
            sum[r] += e;
        }
    }
#pragma unroll
    for (int off = 1; off < 16; off <<= 1)
#pragma unroll
        for (int r = 0; r < 4; ++r) sum[r] += __shfl_xor(sum[r], off);
    float inv[4];
#pragma unroll
    for (int r = 0; r < 4; ++r) inv[r] = 1.f / sum[r];

    __syncthreads();
    u16* Pw = lds0 + wv * 16 * PS_STRIDE;
#pragma unroll
    for (int t = 0; t < KT; ++t)
#pragma unroll
        for (int r = 0; r < 4; ++r)
            Pw[(4 * lg + r) * PS_STRIDE + t * 16 + l15] = f2bf(s[t][r] * inv[r]);

    f32x4 o[4] = {};
#pragma unroll
    for (int ks = 0; ks < 7; ++ks) {
        bf16x8 pa = *(const bf16x8*)(Pw + l15 * PS_STRIDE + ks * 32 + lg * 8);
#pragma unroll
        for (int dt = 0; dt < 4; ++dt) {
            bf16x8 bv = *(const bf16x8*)((const char*)Vt + (size_t)(dt * 16 + l15) * (VT_STRIDE * 2) + ks * 64 + lg * 16);
            o[dt] = __builtin_amdgcn_mfma_f32_16x16x32_bf16(pa, bv, o[dt], 0, 0, 0);
        }
    }
#pragma unroll
    for (int dt = 0; dt < 4; ++dt)
#pragma unroll
        for (int r = 0; r < 4; ++r) {
            int q = q0 + 4 * lg + r;
            if (q < NGL) Z[((size_t)b * NT + q) * CDIM + h * 64 + dt * 16 + l15] = f2bf(o[dt][r]);
        }
}

// ---------------- Neighborhood attention ----------------
__global__ __launch_bounds__(64) void attn_neigh(const u16* __restrict__ qkv, const float* __restrict__ ps,
                                                 u16* __restrict__ Z) {
    int blk = blockIdx.x;
    int b = blk >> 6, m = blk & 63;
    int lane = threadIdx.x;
    float px = ps[((size_t)b * 64 + m) * 2 + 0] * (1.f / 16.f);
    float py = ps[((size_t)b * 64 + m) * 2 + 1] * (1.f / 16.f);
    int c0 = min(max((int)floorf(px), 0), 13);
    int c1 = min(max((int)ceilf(px), 0), 13);
    int r0 = min(max((int)floorf(py), 0), 13);
    int r1 = min(max((int)ceilf(py), 0), 13);
    int tok[4];
    tok[0] = 1 + r0 * 14 + c0;
    tok[1] = 1 + r1 * 14 + c0;
    tok[2] = 1 + r0 * 14 + c1;
    tok[3] = 1 + r1 * 14 + c1;
    const size_t rowq = ((size_t)b * NT + NGL + m) * 2304;
#pragma unroll 1
    for (int h = 0; h < NHEAD; ++h) {
        float qv = bf2f(qkv[rowq + h * 64 + lane]);
        float a[4];
#pragma unroll
        for (int j = 0; j < 4; ++j) {
            float p = qv * bf2f(qkv[((size_t)b * NT + tok[j]) * 2304 + 768 + h * 64 + lane]);
#pragma unroll
            for (int off = 32; off; off >>= 1) p += __shfl_xor(p, off);
            a[j] = p;
        }
        float mx = fmaxf(fmaxf(a[0], a[1]), fmaxf(a[2], a[3]));
        float e0 = expf(a[0] - mx), e1 = expf(a[1] - mx), e2 = expf(a[2] - mx), e3 = expf(a[3] - mx);
        float inv = 1.f / (e0 + e1 + e2 + e3);
        float v0 = bf2f(qkv[((size_t)b * NT + tok[0]) * 2304 + 1536 + h * 64 + lane]);
        float v1 = bf2f(qkv[((size_t)b * NT + tok[1]) * 2304 + 1536 + h * 64 + lane]);
        float v2 = bf2f(qkv[((size_t)b * NT + tok[2]) * 2304 + 1536 + h * 64 + lane]);
        float v3 = bf2f(qkv[((size_t)b * NT + tok[3]) * 2304 + 1536 + h * 64 + lane]);
        float o = (e0 * v0 + e1 * v1 + e2 * v2 + e3 * v3) * inv;
        Z[((size_t)b * NT + NGL + m) * CDIM + h * 64 + lane] = f2bf(o);
    }
}

extern "C" void kernel_launch(void* const* d_in, const int* in_sizes, int n_in,
                              void* d_out, int out_size, void* d_ws, size_t ws_size,
                              hipStream_t stream) {
    const float* x      = (const float*)d_in[0];
    const float* ps     = (const float*)d_in[1];
    const float* n1w    = (const float*)d_in[3];
    const float* n1b    = (const float*)d_in[4];
    const float* qkv_w  = (const float*)d_in[5];
    const float* proj_w = (const float*)d_in[6];
    const float* proj_b = (const float*)d_in[7];
    const float* n2w    = (const float*)d_in[8];
    const float* n2b    = (const float*)d_in[9];
    const float* fc1_w  = (const float*)d_in[10];
    const float* fc1_b  = (const float*)d_in[11];
    const float* fc2_w  = (const float*)d_in[12];
    const float* fc2_b  = (const float*)d_in[13];

    char* ws = (char*)d_ws;
    const int M = 32 * NT;  // 8352
    u16* hbuf  = (u16*)ws;                               // 12,828,672 B
    u16* qkvb  = (u16*)(ws + 12828672);                  // 38,486,016 B
    u16* Zb    = (u16*)(ws + 12828672 + 38486016);       // 12,828,672 B
    u16* Gb    = (u16*)(ws + 12828672);                  // 51,314,688 B (aliases qkv+Z, both dead)
    float* x1  = (float*)(ws + 64143360);                // 25,657,344 B
    u16* wq    = (u16*)(ws + 89800704);
    u16* wp    = wq + 2304 * 768;
    u16* w1    = wp + 768 * 768;
    u16* w2    = w1 + 3072 * 768;

    CvArgs cv;
    cv.in[0] = qkv_w;  cv.out[0] = wq; cv.n4[0] = 2304 * 768 / 4;
    cv.in[1] = proj_w; cv.out[1] = wp; cv.n4[1] = 768 * 768 / 4;
    cv.in[2] = fc1_w;  cv.out[2] = w1; cv.n4[2] = 3072 * 768 / 4;
    cv.in[3] = fc2_w;  cv.out[3] = w2; cv.n4[3] = 768 * 3072 / 4;
    convk4<<<dim3((3072 * 768 / 4 + 255) / 256, 4), 256, 0, stream>>>(cv);

    ln_k<<<M, 256, 0, stream>>>(x, n1w, n1b, hbuf);
    gemm5<0><<<33 * 9, 512, 0, stream>>>(hbuf, wq, M, 2304, 768, 9, nullptr, qkvb);
    attn_global_mfma<<<32 * NHEAD * 4, 256, 0, stream>>>(qkvb, Zb);
    attn_neigh<<<32 * 64, 64, 0, stream>>>(qkvb, ps, Zb);
    gemm4n<1><<<66 * 6, 256, 0, stream>>>(Zb, wp, M, 768, 768, 6, proj_b, x, x1);
    ln_k<<<M, 256, 0, stream>>>(x1, n2w, n2b, hbuf);
    gemm5<2><<<33 * 12, 512, 0, stream>>>(hbuf, w1, M, 3072, 768, 12, fc1_b, Gb);
    gemm4n<1><<<66 * 6, 256, 0, stream>>>(Gb, w2, M, 768, 3072, 6, fc2_b, x1, (float*)d_out);
}